// Round 1
// baseline (480.980 us; speedup 1.0000x reference)
//
#include <hip/hip_runtime.h>
#include <hip/hip_bf16.h>

#define DH 1024      // hidden dim
#define NE 8         // experts
#define NT 8192      // tokens (4*2048)
#define NTK 16384    // tokens * top-k

typedef __bf16 bf16x8 __attribute__((ext_vector_type(8)));
typedef float f32x4 __attribute__((ext_vector_type(4)));
typedef unsigned short u16;
typedef u16 u16x8 __attribute__((ext_vector_type(8)));
typedef u16 u16x4 __attribute__((ext_vector_type(4)));

__device__ __forceinline__ u16 f2bf(float f) {
  union { float f; unsigned u; } v; v.f = f;
  return (u16)((v.u + 0x7fffu + ((v.u >> 16) & 1u)) >> 16);  // RNE
}
__device__ __forceinline__ float bf2f(u16 h) {
  union { unsigned u; float f; } v; v.u = ((unsigned)h) << 16;
  return v.f;
}
__device__ __forceinline__ float gelu_tanh(float v) {
  // jax.nn.gelu default: approximate=True (tanh form)
  float y = 0.7978845608028654f * (v + 0.044715f * v * v * v);
  float t = 1.f - 2.f / (1.f + __expf(2.f * y));   // tanh(y)
  return 0.5f * v * (1.f + t);
}

// ---- weight transpose + bf16 convert: w[e][d][n] (f32) -> wt[e][n][d] (bf16)
__global__ __launch_bounds__(256) void prep_transpose(
    const float* __restrict__ w1, const float* __restrict__ w2,
    u16* __restrict__ w1t, u16* __restrict__ w2t) {
  __shared__ float tile[64][65];
  int z = blockIdx.z;  // 0..7 -> w1, 8..15 -> w2
  const float* src = (z < NE) ? (w1 + (size_t)z * DH * DH) : (w2 + (size_t)(z - NE) * DH * DH);
  u16* dst = (z < NE) ? (w1t + (size_t)z * DH * DH) : (w2t + (size_t)(z - NE) * DH * DH);
  int d0 = blockIdx.y * 64, n0 = blockIdx.x * 64;
  int tid = threadIdx.x;
  int c = tid & 63, r = tid >> 6;
#pragma unroll
  for (int it = 0; it < 16; ++it) {
    int rr = r + it * 4;
    tile[rr][c] = src[(size_t)(d0 + rr) * DH + n0 + c];
  }
  __syncthreads();
#pragma unroll
  for (int it = 0; it < 16; ++it) {
    int rr = r + it * 4;
    dst[(size_t)(n0 + rr) * DH + d0 + c] = f2bf(tile[c][rr]);
  }
}

// ---- router: one wave per token. fp32 logits, softmax, top-2.
__global__ __launch_bounds__(256) void router_kernel(
    const float* __restrict__ x, const float* __restrict__ wr,
    float* __restrict__ logits_out, int* __restrict__ tkidx,
    float* __restrict__ tkp, int* __restrict__ counts) {
  int t = blockIdx.x * 4 + (threadIdx.x >> 6);
  int lane = threadIdx.x & 63;
  float acc[8] = {0.f, 0.f, 0.f, 0.f, 0.f, 0.f, 0.f, 0.f};
  const float* xrow = x + (size_t)t * DH;
  for (int d = lane; d < DH; d += 64) {
    float xv = xrow[d];
    const float4* wp = (const float4*)(wr + (size_t)d * NE);
    float4 w0 = wp[0], w1 = wp[1];
    acc[0] += xv * w0.x; acc[1] += xv * w0.y; acc[2] += xv * w0.z; acc[3] += xv * w0.w;
    acc[4] += xv * w1.x; acc[5] += xv * w1.y; acc[6] += xv * w1.z; acc[7] += xv * w1.w;
  }
#pragma unroll
  for (int off = 32; off; off >>= 1) {
#pragma unroll
    for (int e = 0; e < 8; ++e) acc[e] += __shfl_xor(acc[e], off, 64);
  }
  if (lane == 0) {
    float m1 = acc[0]; int i1 = 0;
#pragma unroll
    for (int e = 1; e < 8; ++e) if (acc[e] > m1) { m1 = acc[e]; i1 = e; }
    float m2 = -3.4e38f; int i2 = 0;
#pragma unroll
    for (int e = 0; e < 8; ++e) if (e != i1 && acc[e] > m2) { m2 = acc[e]; i2 = e; }
    float den = 0.f;
#pragma unroll
    for (int e = 0; e < 8; ++e) den += expf(acc[e] - m1);
    float p1 = 1.0f / den;
    float p2 = expf(m2 - m1) / den;
#pragma unroll
    for (int e = 0; e < 8; ++e) logits_out[(size_t)t * NE + e] = acc[e];
    tkidx[2 * t] = i1; tkidx[2 * t + 1] = i2;
    tkp[2 * t] = p1;  tkp[2 * t + 1] = p2;
    atomicAdd(&counts[i1], 1);
    atomicAdd(&counts[i2], 1);
  }
}

__global__ void offsets_kernel(const int* __restrict__ counts,
                               int* __restrict__ offs, int* __restrict__ cur) {
  if (threadIdx.x == 0) {
    int s = 0;
    for (int e = 0; e < NE; ++e) { offs[e] = s; s += counts[e]; cur[e] = 0; }
    offs[NE] = s;
  }
}

__global__ __launch_bounds__(256) void scatter_kernel(
    const int* __restrict__ tkidx, const float* __restrict__ tkp,
    const int* __restrict__ offs, int* __restrict__ cur,
    int* __restrict__ rows, int* __restrict__ posof, float* __restrict__ pp) {
  int gid = blockIdx.x * 256 + threadIdx.x;  // < NTK
  int e = tkidx[gid];
  int pos = offs[e] + atomicAdd(&cur[e], 1);
  rows[pos] = gid >> 1;
  posof[gid] = pos;
  pp[pos] = tkp[gid];
}

// ---- grouped GEMM1: h[pos] = gelu(x[rows[pos]] @ w1[e] + b1[e])   (bf16 out)
__global__ __launch_bounds__(256) void gemm1_kernel(
    const float* __restrict__ x, const u16* __restrict__ w1t,
    const float* __restrict__ b1, const int* __restrict__ counts,
    const int* __restrict__ offs, const int* __restrict__ rows,
    u16* __restrict__ h) {
  int e = blockIdx.z;
  int cnt = counts[e];
  int m0 = blockIdx.y * 64;
  if (m0 >= cnt) return;
  int n0 = blockIdx.x * 64;
  int seg = offs[e];
  const int* rowsSeg = rows + seg;
  const u16* bsrc = w1t + (size_t)e * DH * DH;

  __shared__ __attribute__((aligned(16))) u16 As[64][72];
  __shared__ __attribute__((aligned(16))) u16 Bs[64][72];

  int tid = threadIdx.x;
  int c8 = (tid & 7) * 8;
  int r0 = tid >> 3;  // 0..31
  int gi0 = m0 + r0, gi1 = gi0 + 32;
  int ra = rowsSeg[gi0 < cnt ? gi0 : cnt - 1];
  int rb = rowsSeg[gi1 < cnt ? gi1 : cnt - 1];
  const float* xa = x + (size_t)ra * DH + c8;
  const float* xb = x + (size_t)rb * DH + c8;
  const u16* ba = bsrc + (size_t)(n0 + r0) * DH + c8;
  const u16* bb = ba + (size_t)32 * DH;

  int lane = tid & 63;
  int wv = tid >> 6;
  int wr = (wv >> 1) * 32, wc = (wv & 1) * 32;
  int lr = lane & 15;
  int kg8 = (lane >> 4) * 8;

  f32x4 acc[2][2] = {};

  for (int k0 = 0; k0 < DH; k0 += 64) {
    float4 fa0 = *(const float4*)(xa + k0);
    float4 fa1 = *(const float4*)(xa + k0 + 4);
    float4 fb0 = *(const float4*)(xb + k0);
    float4 fb1 = *(const float4*)(xb + k0 + 4);
    u16x8 pa, pb;
    pa[0] = f2bf(fa0.x); pa[1] = f2bf(fa0.y); pa[2] = f2bf(fa0.z); pa[3] = f2bf(fa0.w);
    pa[4] = f2bf(fa1.x); pa[5] = f2bf(fa1.y); pa[6] = f2bf(fa1.z); pa[7] = f2bf(fa1.w);
    pb[0] = f2bf(fb0.x); pb[1] = f2bf(fb0.y); pb[2] = f2bf(fb0.z); pb[3] = f2bf(fb0.w);
    pb[4] = f2bf(fb1.x); pb[5] = f2bf(fb1.y); pb[6] = f2bf(fb1.z); pb[7] = f2bf(fb1.w);
    *(u16x8*)&As[r0][c8] = pa;
    *(u16x8*)&As[r0 + 32][c8] = pb;
    *(u16x8*)&Bs[r0][c8] = *(const u16x8*)(ba + k0);
    *(u16x8*)&Bs[r0 + 32][c8] = *(const u16x8*)(bb + k0);
    __syncthreads();
#pragma unroll
    for (int ks = 0; ks < 64; ks += 32) {
      bf16x8 a0 = *(const bf16x8*)&As[wr + lr][ks + kg8];
      bf16x8 a1 = *(const bf16x8*)&As[wr + 16 + lr][ks + kg8];
      bf16x8 b0 = *(const bf16x8*)&Bs[wc + lr][ks + kg8];
      bf16x8 b1v = *(const bf16x8*)&Bs[wc + 16 + lr][ks + kg8];
      acc[0][0] = __builtin_amdgcn_mfma_f32_16x16x32_bf16(a0, b0, acc[0][0], 0, 0, 0);
      acc[0][1] = __builtin_amdgcn_mfma_f32_16x16x32_bf16(a0, b1v, acc[0][1], 0, 0, 0);
      acc[1][0] = __builtin_amdgcn_mfma_f32_16x16x32_bf16(a1, b0, acc[1][0], 0, 0, 0);
      acc[1][1] = __builtin_amdgcn_mfma_f32_16x16x32_bf16(a1, b1v, acc[1][1], 0, 0, 0);
    }
    __syncthreads();
  }

  const float* b1e = b1 + (size_t)e * DH;
  int r4 = (lane >> 4) * 4;
#pragma unroll
  for (int m = 0; m < 2; ++m) {
#pragma unroll
    for (int n = 0; n < 2; ++n) {
      int col = n0 + wc + n * 16 + lr;
      float bias = b1e[col];
#pragma unroll
      for (int j = 0; j < 4; ++j) {
        int gr = m0 + wr + m * 16 + r4 + j;
        if (gr < cnt) {
          float v = acc[m][n][j] + bias;
          h[(size_t)(seg + gr) * DH + col] = f2bf(gelu_tanh(v));
        }
      }
    }
  }
}

// ---- grouped GEMM2: eo[pos] = h[pos] @ w2[e]  (bf16 out), or atomic fallback
template <int MODE>
__global__ __launch_bounds__(256) void gemm2_kernel(
    const u16* __restrict__ h, const u16* __restrict__ w2t,
    const float* __restrict__ b2, const int* __restrict__ counts,
    const int* __restrict__ offs, const float* __restrict__ pp,
    const int* __restrict__ rows, u16* __restrict__ eo, float* __restrict__ out) {
  int e = blockIdx.z;
  int cnt = counts[e];
  int m0 = blockIdx.y * 64;
  if (m0 >= cnt) return;
  int n0 = blockIdx.x * 64;
  int seg = offs[e];
  const u16* bsrc = w2t + (size_t)e * DH * DH;

  __shared__ __attribute__((aligned(16))) u16 As[64][72];
  __shared__ __attribute__((aligned(16))) u16 Bs[64][72];

  int tid = threadIdx.x;
  int c8 = (tid & 7) * 8;
  int r0 = tid >> 3;
  int gi0 = m0 + r0, gi1 = gi0 + 32;
  int ia = gi0 < cnt ? gi0 : cnt - 1;
  int ib = gi1 < cnt ? gi1 : cnt - 1;
  const u16* ha = h + (size_t)(seg + ia) * DH + c8;
  const u16* hb = h + (size_t)(seg + ib) * DH + c8;
  const u16* ba = bsrc + (size_t)(n0 + r0) * DH + c8;
  const u16* bb = ba + (size_t)32 * DH;

  int lane = tid & 63;
  int wv = tid >> 6;
  int wr = (wv >> 1) * 32, wc = (wv & 1) * 32;
  int lr = lane & 15;
  int kg8 = (lane >> 4) * 8;

  f32x4 acc[2][2] = {};

  for (int k0 = 0; k0 < DH; k0 += 64) {
    *(u16x8*)&As[r0][c8] = *(const u16x8*)(ha + k0);
    *(u16x8*)&As[r0 + 32][c8] = *(const u16x8*)(hb + k0);
    *(u16x8*)&Bs[r0][c8] = *(const u16x8*)(ba + k0);
    *(u16x8*)&Bs[r0 + 32][c8] = *(const u16x8*)(bb + k0);
    __syncthreads();
#pragma unroll
    for (int ks = 0; ks < 64; ks += 32) {
      bf16x8 a0 = *(const bf16x8*)&As[wr + lr][ks + kg8];
      bf16x8 a1 = *(const bf16x8*)&As[wr + 16 + lr][ks + kg8];
      bf16x8 b0 = *(const bf16x8*)&Bs[wc + lr][ks + kg8];
      bf16x8 b1v = *(const bf16x8*)&Bs[wc + 16 + lr][ks + kg8];
      acc[0][0] = __builtin_amdgcn_mfma_f32_16x16x32_bf16(a0, b0, acc[0][0], 0, 0, 0);
      acc[0][1] = __builtin_amdgcn_mfma_f32_16x16x32_bf16(a0, b1v, acc[0][1], 0, 0, 0);
      acc[1][0] = __builtin_amdgcn_mfma_f32_16x16x32_bf16(a1, b0, acc[1][0], 0, 0, 0);
      acc[1][1] = __builtin_amdgcn_mfma_f32_16x16x32_bf16(a1, b1v, acc[1][1], 0, 0, 0);
    }
    __syncthreads();
  }

  int r4 = (lane >> 4) * 4;
  const float* b2e = b2 + (size_t)e * DH;
#pragma unroll
  for (int m = 0; m < 2; ++m) {
#pragma unroll
    for (int n = 0; n < 2; ++n) {
      int col = n0 + wc + n * 16 + lr;
#pragma unroll
      for (int j = 0; j < 4; ++j) {
        int gr = m0 + wr + m * 16 + r4 + j;
        if (gr < cnt) {
          if (MODE == 0) {
            eo[(size_t)(seg + gr) * DH + col] = f2bf(acc[m][n][j]);
          } else {
            int t = rows[seg + gr];
            float p = pp[seg + gr];
            atomicAdd(&out[(size_t)t * DH + col], p * (acc[m][n][j] + b2e[col]));
          }
        }
      }
    }
  }
}

// ---- combine: out[t] = p0*(eo[q0]+b2[e0]) + p1*(eo[q1]+b2[e1])
__global__ __launch_bounds__(256) void combine_kernel(
    const u16* __restrict__ eo, const float* __restrict__ b2,
    const int* __restrict__ tkidx, const float* __restrict__ tkp,
    const int* __restrict__ posof, float* __restrict__ out) {
  int gid = blockIdx.x * 256 + threadIdx.x;  // NT*256 threads
  int t = gid >> 8;
  int n = (gid & 255) * 4;
  int e0 = tkidx[2 * t], e1 = tkidx[2 * t + 1];
  float p0 = tkp[2 * t], p1 = tkp[2 * t + 1];
  int q0 = posof[2 * t], q1 = posof[2 * t + 1];
  u16x4 a = *(const u16x4*)(eo + (size_t)q0 * DH + n);
  u16x4 b = *(const u16x4*)(eo + (size_t)q1 * DH + n);
  float4 ba0 = *(const float4*)(b2 + (size_t)e0 * DH + n);
  float4 ba1 = *(const float4*)(b2 + (size_t)e1 * DH + n);
  float4 o;
  o.x = p0 * (bf2f(a[0]) + ba0.x) + p1 * (bf2f(b[0]) + ba1.x);
  o.y = p0 * (bf2f(a[1]) + ba0.y) + p1 * (bf2f(b[1]) + ba1.y);
  o.z = p0 * (bf2f(a[2]) + ba0.z) + p1 * (bf2f(b[2]) + ba1.z);
  o.w = p0 * (bf2f(a[3]) + ba0.w) + p1 * (bf2f(b[3]) + ba1.w);
  *(float4*)(out + (size_t)t * DH + n) = o;
}

extern "C" void kernel_launch(void* const* d_in, const int* in_sizes, int n_in,
                              void* d_out, int out_size, void* d_ws, size_t ws_size,
                              hipStream_t stream) {
  const float* x = (const float*)d_in[0];
  const float* w_router = (const float*)d_in[1];
  const float* w1 = (const float*)d_in[2];
  const float* b1 = (const float*)d_in[3];
  const float* w2 = (const float*)d_in[4];
  const float* b2 = (const float*)d_in[5];
  float* out = (float*)d_out;                 // combined [NT][DH]
  float* logits = out + (size_t)NT * DH;      // [NT][NE]

  char* ws = (char*)d_ws;
  size_t off = 0;
  auto alloc = [&](size_t bytes) -> void* {
    void* p = ws + off;
    off = (off + bytes + 255) & ~(size_t)255;
    return p;
  };
  int* ctrl = (int*)alloc(256);  // counts[8] | cur[8] | offs[9]
  int* counts = ctrl;
  int* cur = ctrl + 8;
  int* offs = ctrl + 16;
  int* tkidx = (int*)alloc((size_t)NTK * 4);
  float* tkp = (float*)alloc((size_t)NTK * 4);
  int* rows = (int*)alloc((size_t)NTK * 4);
  int* posof = (int*)alloc((size_t)NTK * 4);
  float* pp = (float*)alloc((size_t)NTK * 4);
  u16* w1t = (u16*)alloc((size_t)NE * DH * DH * 2);
  u16* w2t = (u16*)alloc((size_t)NE * DH * DH * 2);
  u16* hbuf = (u16*)alloc((size_t)NTK * DH * 2);
  u16* eo = (u16*)alloc((size_t)NTK * DH * 2);
  bool use_eo = (ws_size >= off);

  hipMemsetAsync(ctrl, 0, 256, stream);
  if (!use_eo) hipMemsetAsync(out, 0, (size_t)NT * DH * 4, stream);

  prep_transpose<<<dim3(16, 16, 16), 256, 0, stream>>>(w1, w2, w1t, w2t);
  router_kernel<<<NT / 4, 256, 0, stream>>>(x, w_router, logits, tkidx, tkp, counts);
  offsets_kernel<<<1, 64, 0, stream>>>(counts, offs, cur);
  scatter_kernel<<<NTK / 256, 256, 0, stream>>>(tkidx, tkp, offs, cur, rows, posof, pp);
  gemm1_kernel<<<dim3(16, 128, 8), 256, 0, stream>>>(x, w1t, b1, counts, offs, rows, hbuf);
  if (use_eo) {
    gemm2_kernel<0><<<dim3(16, 128, 8), 256, 0, stream>>>(hbuf, w2t, b2, counts, offs, pp, rows, eo, out);
    combine_kernel<<<NT, 256, 0, stream>>>(eo, b2, tkidx, tkp, posof, out);
  } else {
    gemm2_kernel<1><<<dim3(16, 128, 8), 256, 0, stream>>>(hbuf, w2t, b2, counts, offs, pp, rows, eo, out);
  }
}

// Round 2
// 221.159 us; speedup vs baseline: 2.1748x; 2.1748x over previous
//
#include <hip/hip_runtime.h>
#include <hip/hip_bf16.h>

#define DH 1024      // hidden dim
#define NE 8         // experts
#define NT 8192      // tokens (4*2048)
#define NTK 16384    // tokens * top-k

typedef __bf16 bf16x8 __attribute__((ext_vector_type(8)));
typedef float f32x4 __attribute__((ext_vector_type(4)));
typedef unsigned short u16;
typedef u16 u16x8 __attribute__((ext_vector_type(8)));
typedef u16 u16x4 __attribute__((ext_vector_type(4)));

__device__ __forceinline__ u16 f2bf(float f) {
  union { float f; unsigned u; } v; v.f = f;
  return (u16)((v.u + 0x7fffu + ((v.u >> 16) & 1u)) >> 16);  // RNE
}
__device__ __forceinline__ float bf2f(u16 h) {
  union { unsigned u; float f; } v; v.u = ((unsigned)h) << 16;
  return v.f;
}
__device__ __forceinline__ float gelu_tanh(float v) {
  float y = 0.7978845608028654f * (v + 0.044715f * v * v * v);
  float t = 1.f - 2.f / (1.f + __expf(2.f * y));   // tanh(y)
  return 0.5f * v * (1.f + t);
}

// ---- weight transpose + bf16 convert: w[e][d][n] (f32) -> wt[e][n][d] (bf16)
__global__ __launch_bounds__(256) void prep_transpose(
    const float* __restrict__ w1, const float* __restrict__ w2,
    u16* __restrict__ w1t, u16* __restrict__ w2t) {
  __shared__ float tile[64][65];
  int z = blockIdx.z;  // 0..7 -> w1, 8..15 -> w2
  const float* src = (z < NE) ? (w1 + (size_t)z * DH * DH) : (w2 + (size_t)(z - NE) * DH * DH);
  u16* dst = (z < NE) ? (w1t + (size_t)z * DH * DH) : (w2t + (size_t)(z - NE) * DH * DH);
  int d0 = blockIdx.y * 64, n0 = blockIdx.x * 64;
  int tid = threadIdx.x;
  int c = tid & 63, r = tid >> 6;
#pragma unroll
  for (int it = 0; it < 16; ++it) {
    int rr = r + it * 4;
    tile[rr][c] = src[(size_t)(d0 + rr) * DH + n0 + c];
  }
  __syncthreads();
#pragma unroll
  for (int it = 0; it < 16; ++it) {
    int rr = r + it * 4;
    dst[(size_t)(n0 + rr) * DH + d0 + c] = f2bf(tile[c][rr]);
  }
}

// ---- x f32 -> bf16 (contiguous)
__global__ __launch_bounds__(256) void convert_x(const float* __restrict__ x,
                                                 u16* __restrict__ xb) {
  size_t gid = (size_t)blockIdx.x * 256 + threadIdx.x;  // one per 8 elems
  const float4* p = (const float4*)(x + gid * 8);
  float4 f0 = p[0], f1 = p[1];
  u16x8 o;
  o[0] = f2bf(f0.x); o[1] = f2bf(f0.y); o[2] = f2bf(f0.z); o[3] = f2bf(f0.w);
  o[4] = f2bf(f1.x); o[5] = f2bf(f1.y); o[6] = f2bf(f1.z); o[7] = f2bf(f1.w);
  *(u16x8*)(xb + gid * 8) = o;
}

// ---- router: 32 tokens/block (8 per wave). fp32. LDS-staged w_router^T.
// Per-block LDS histogram -> 8 global atomics per block.
__global__ __launch_bounds__(256) void router_kernel(
    const float* __restrict__ x, const float* __restrict__ wr,
    float* __restrict__ logits_out, int* __restrict__ tkidx,
    float* __restrict__ tkp, int* __restrict__ counts) {
  __shared__ float wsh[NE][DH + 8];
  __shared__ int hist[NE];
  int tid = threadIdx.x;
  for (int i = tid; i < DH * NE; i += 256) {
    int d = i >> 3, e = i & 7;
    wsh[e][d] = wr[i];
  }
  if (tid < NE) hist[tid] = 0;
  __syncthreads();

  int lane = tid & 63;
  int wv = tid >> 6;
  int t0 = blockIdx.x * 32 + wv * 8;
#pragma unroll 1
  for (int i = 0; i < 8; ++i) {
    int t = t0 + i;
    const float4* xp = (const float4*)(x + (size_t)t * DH);
    float a[8] = {0.f, 0.f, 0.f, 0.f, 0.f, 0.f, 0.f, 0.f};
#pragma unroll
    for (int it = 0; it < 4; ++it) {
      float4 xv = xp[it * 64 + lane];
      int d0 = (it * 64 + lane) * 4;
#pragma unroll
      for (int e = 0; e < 8; ++e) {
        float4 w4 = *(const float4*)&wsh[e][d0];
        a[e] += xv.x * w4.x + xv.y * w4.y + xv.z * w4.z + xv.w * w4.w;
      }
    }
#pragma unroll
    for (int off = 32; off; off >>= 1) {
#pragma unroll
      for (int e = 0; e < 8; ++e) a[e] += __shfl_xor(a[e], off, 64);
    }
    if (lane < 8) logits_out[(size_t)t * NE + lane] = a[lane];
    if (lane == 0) {
      float m1 = a[0]; int i1 = 0;
#pragma unroll
      for (int e = 1; e < 8; ++e) if (a[e] > m1) { m1 = a[e]; i1 = e; }
      float m2 = -3.4e38f; int i2 = 0;
#pragma unroll
      for (int e = 0; e < 8; ++e) if (e != i1 && a[e] > m2) { m2 = a[e]; i2 = e; }
      float den = 0.f;
#pragma unroll
      for (int e = 0; e < 8; ++e) den += expf(a[e] - m1);
      tkidx[2 * t] = i1; tkidx[2 * t + 1] = i2;
      tkp[2 * t] = 1.0f / den;
      tkp[2 * t + 1] = expf(m2 - m1) / den;
      atomicAdd(&hist[i1], 1);
      atomicAdd(&hist[i2], 1);
    }
  }
  __syncthreads();
  if (tid < NE) atomicAdd(&counts[tid], hist[tid]);
}

__global__ void offsets_kernel(const int* __restrict__ counts,
                               int* __restrict__ offs, int* __restrict__ cur) {
  if (threadIdx.x == 0) {
    int s = 0;
    for (int e = 0; e < NE; ++e) { offs[e] = s; s += counts[e]; cur[e] = 0; }
    offs[NE] = s;
  }
}

// ---- scatter: block-hierarchical ranks; 8 global atomics per block (16 blocks).
__global__ __launch_bounds__(1024) void scatter_kernel(
    const int* __restrict__ tkidx, const float* __restrict__ tkp,
    const int* __restrict__ offs, int* __restrict__ cur,
    int* __restrict__ rows, int* __restrict__ posof, float* __restrict__ pp) {
  __shared__ int h[NE];
  __shared__ int base[NE];
  int tid = threadIdx.x;
  int gid = blockIdx.x * 1024 + tid;  // < NTK
  if (tid < NE) h[tid] = 0;
  __syncthreads();
  int e = tkidx[gid];
  int myrank = atomicAdd(&h[e], 1);
  __syncthreads();
  if (tid < NE) base[tid] = atomicAdd(&cur[tid], h[tid]);
  __syncthreads();
  int pos = offs[e] + base[e] + myrank;
  rows[pos] = gid >> 1;
  posof[gid] = pos;
  pp[pos] = tkp[gid];
}

// ---- grouped GEMM, 128x128 tile, BK=64, 4 waves (64x64 each, 4x4 frags)
// GELU=1: A = xb gathered via rows[]; out = gelu(A@W + b)   -> hbuf
// GELU=0: A = hbuf direct;           out = A@W + b          -> eo
template <int GELU>
__global__ __launch_bounds__(256) void gemm_kernel(
    const u16* __restrict__ A, const u16* __restrict__ W,
    const float* __restrict__ bias, const int* __restrict__ counts,
    const int* __restrict__ offs, const int* __restrict__ rows,
    u16* __restrict__ outb) {
  int e = blockIdx.z;
  int cnt = counts[e];
  int m0 = blockIdx.y * 128;
  if (m0 >= cnt) return;
  int n0 = blockIdx.x * 128;
  int seg = offs[e];

  __shared__ __attribute__((aligned(16))) u16 As[128][72];
  __shared__ __attribute__((aligned(16))) u16 Bs[128][72];

  int tid = threadIdx.x;
  int arow = tid >> 1;           // 0..127
  int kh = (tid & 1) * 32;       // 0 or 32

  int gi = m0 + arow;
  int clamp = gi < cnt ? gi : cnt - 1;
  const u16* aptr;
  if (GELU) {
    aptr = A + (size_t)rows[seg + clamp] * DH + kh;
  } else {
    aptr = A + (size_t)(seg + clamp) * DH + kh;
  }
  const u16* bptr = W + (size_t)e * DH * DH + (size_t)(n0 + arow) * DH + kh;

  int lane = tid & 63;
  int wv = tid >> 6;
  int wrr = (wv >> 1) * 64, wcc = (wv & 1) * 64;
  int lr = lane & 15;
  int kg8 = (lane >> 4) * 8;

  f32x4 acc[4][4] = {};

  for (int k0 = 0; k0 < DH; k0 += 64) {
    u16x8 av[4], bv[4];
#pragma unroll
    for (int j = 0; j < 4; ++j) {
      av[j] = *(const u16x8*)(aptr + k0 + j * 8);
      bv[j] = *(const u16x8*)(bptr + k0 + j * 8);
    }
    __syncthreads();
#pragma unroll
    for (int j = 0; j < 4; ++j) {
      *(u16x8*)&As[arow][kh + j * 8] = av[j];
      *(u16x8*)&Bs[arow][kh + j * 8] = bv[j];
    }
    __syncthreads();
#pragma unroll
    for (int ks = 0; ks < 64; ks += 32) {
      bf16x8 af[4], bfv[4];
#pragma unroll
      for (int m = 0; m < 4; ++m) af[m] = *(const bf16x8*)&As[wrr + m * 16 + lr][ks + kg8];
#pragma unroll
      for (int n = 0; n < 4; ++n) bfv[n] = *(const bf16x8*)&Bs[wcc + n * 16 + lr][ks + kg8];
#pragma unroll
      for (int m = 0; m < 4; ++m)
#pragma unroll
        for (int n = 0; n < 4; ++n)
          acc[m][n] = __builtin_amdgcn_mfma_f32_16x16x32_bf16(af[m], bfv[n], acc[m][n], 0, 0, 0);
    }
  }

  int r4 = (lane >> 4) * 4;
  const float* be = bias + (size_t)e * DH;
#pragma unroll
  for (int m = 0; m < 4; ++m) {
#pragma unroll
    for (int n = 0; n < 4; ++n) {
      int col = n0 + wcc + n * 16 + lr;
      float bvv = be[col];
#pragma unroll
      for (int j = 0; j < 4; ++j) {
        int gr = m0 + wrr + m * 16 + r4 + j;
        if (gr < cnt) {
          float v = acc[m][n][j] + bvv;
          if (GELU) v = gelu_tanh(v);
          outb[(size_t)(seg + gr) * DH + col] = f2bf(v);
        }
      }
    }
  }
}

// ---- combine: out[t] = p0*eo[q0] + p1*eo[q1]   (bias already in eo)
__global__ __launch_bounds__(256) void combine_kernel(
    const u16* __restrict__ eo, const float* __restrict__ tkp,
    const int* __restrict__ posof, float* __restrict__ out) {
  int gid = blockIdx.x * 256 + threadIdx.x;
  int t = gid >> 8;
  int n = (gid & 255) * 4;
  float p0 = tkp[2 * t], p1 = tkp[2 * t + 1];
  int q0 = posof[2 * t], q1 = posof[2 * t + 1];
  u16x4 a = *(const u16x4*)(eo + (size_t)q0 * DH + n);
  u16x4 b = *(const u16x4*)(eo + (size_t)q1 * DH + n);
  float4 o;
  o.x = p0 * bf2f(a[0]) + p1 * bf2f(b[0]);
  o.y = p0 * bf2f(a[1]) + p1 * bf2f(b[1]);
  o.z = p0 * bf2f(a[2]) + p1 * bf2f(b[2]);
  o.w = p0 * bf2f(a[3]) + p1 * bf2f(b[3]);
  *(float4*)(out + (size_t)t * DH + n) = o;
}

extern "C" void kernel_launch(void* const* d_in, const int* in_sizes, int n_in,
                              void* d_out, int out_size, void* d_ws, size_t ws_size,
                              hipStream_t stream) {
  const float* x = (const float*)d_in[0];
  const float* w_router = (const float*)d_in[1];
  const float* w1 = (const float*)d_in[2];
  const float* b1 = (const float*)d_in[3];
  const float* w2 = (const float*)d_in[4];
  const float* b2 = (const float*)d_in[5];
  float* out = (float*)d_out;                 // combined [NT][DH]
  float* logits = out + (size_t)NT * DH;      // [NT][NE]

  char* ws = (char*)d_ws;
  size_t off = 0;
  auto alloc = [&](size_t bytes) -> void* {
    void* p = ws + off;
    off = (off + bytes + 255) & ~(size_t)255;
    return p;
  };
  int* ctrl = (int*)alloc(256);  // counts[8] | cur[8] | offs[9]
  int* counts = ctrl;
  int* cur = ctrl + 8;
  int* offs = ctrl + 16;
  int* tkidx = (int*)alloc((size_t)NTK * 4);
  float* tkp = (float*)alloc((size_t)NTK * 4);
  int* rows = (int*)alloc((size_t)NTK * 4);
  int* posof = (int*)alloc((size_t)NTK * 4);
  float* pp = (float*)alloc((size_t)NTK * 4);
  u16* w1t = (u16*)alloc((size_t)NE * DH * DH * 2);
  u16* w2t = (u16*)alloc((size_t)NE * DH * DH * 2);
  u16* hbuf = (u16*)alloc((size_t)NTK * DH * 2);
  u16* eo = (u16*)alloc((size_t)NTK * DH * 2);  // also aliased as xb (first 16MB)
  u16* xb = eo;  // lifetimes disjoint: xb used before gemm2 writes eo

  hipMemsetAsync(ctrl, 0, 256, stream);

  prep_transpose<<<dim3(16, 16, 16), 256, 0, stream>>>(w1, w2, w1t, w2t);
  convert_x<<<(NT * DH / 8) / 256, 256, 0, stream>>>(x, xb);
  router_kernel<<<NT / 32, 256, 0, stream>>>(x, w_router, logits, tkidx, tkp, counts);
  offsets_kernel<<<1, 64, 0, stream>>>(counts, offs, cur);
  scatter_kernel<<<NTK / 1024, 1024, 0, stream>>>(tkidx, tkp, offs, cur, rows, posof, pp);
  gemm_kernel<1><<<dim3(8, 128, 8), 256, 0, stream>>>(xb, w1t, b1, counts, offs, rows, hbuf);
  gemm_kernel<0><<<dim3(8, 128, 8), 256, 0, stream>>>(hbuf, w2t, b2, counts, offs, rows, eo);
  combine_kernel<<<NT, 256, 0, stream>>>(eo, tkp, posof, out);
}